// Round 14
// baseline (90.693 us; speedup 1.0000x reference)
//
#include <hip/hip_runtime.h>
#include <math.h>

#define BB 64
#define AA 8732
#define DD 85
#define GG 32
#define CC 81
#define TILE 64
#define RPB 4          /* 64-row groups per loss block */
#define NLB 35         /* loss blocks per batch (35*256 = 8960 >= 8732) */

// ---------------- workspace layout (bytes) ----------------
// match:       0        .. 2235392   (B*A int32)
// all_neg:     2235392  .. 4470784   (B*A float)
// partials:    4470784  .. 4479744   (B*NLB float)
// poscnts:     4479744  .. 4488704   (B*NLB int32)
// batch_total: 4488704  .. 4488960   (B float)
// bestp:       4488960  .. 4497152   (B*G int32)
// epoch:       4497152  .. 4497156   (u32; zeroed by k_A blk(0,0))

typedef __attribute__((address_space(3))) unsigned int lds_u32;
typedef const __attribute__((address_space(1))) unsigned int glb_u32;

__device__ __forceinline__ float smoothl1(float d) {
  float ad = fabsf(d);
  return ad < 1.0f ? 0.5f * d * d : ad - 0.5f;
}

__device__ __forceinline__ float frcp(float x) {
  return __builtin_amdgcn_rcpf(x);
}

// ============ kernel A: stage-A threshold matching only ============
// grid (NLB, B), 256 threads; one thread = one anchor.
__global__ __launch_bounds__(256) void k_A(
    const float* __restrict__ anchors, const float* __restrict__ gt_boxes,
    const int* __restrict__ gt_counts, int* __restrict__ match,
    unsigned* __restrict__ epoch)
{
  const int b = blockIdx.y;
  const int count = gt_counts[b];
  __shared__ float gx0[GG], gy0[GG], gx1[GG], gy1[GG], gar[GG];

  if (blockIdx.x == 0 && b == 0 && threadIdx.x == 0) *epoch = 0u;
  if (threadIdx.x < GG) {
    float4 gb = reinterpret_cast<const float4*>(gt_boxes)[b * GG + threadIdx.x];
    float x0 = gb.x - gb.z * 0.5f, y0 = gb.y - gb.w * 0.5f;
    float x1 = gb.x + gb.z * 0.5f, y1 = gb.y + gb.w * 0.5f;
    gx0[threadIdx.x] = x0; gy0[threadIdx.x] = y0;
    gx1[threadIdx.x] = x1; gy1[threadIdx.x] = y1;
    gar[threadIdx.x] = (x1 - x0) * (y1 - y0);
  }
  __syncthreads();
  const int a = blockIdx.x * 256 + threadIdx.x;
  if (a >= AA) return;

  float4 an = reinterpret_cast<const float4*>(anchors)[a];
  float ax0 = an.x - an.z * 0.5f, ay0 = an.y - an.w * 0.5f;
  float ax1 = an.x + an.z * 0.5f, ay1 = an.y + an.w * 0.5f;
  float aar = (ax1 - ax0) * (ay1 - ay0);
  float best = -1.0f; int bi = 0;
  for (int g = 0; g < count; ++g) {
    float iw = fmaxf(fminf(gx1[g], ax1) - fmaxf(gx0[g], ax0), 0.0f);
    float ih = fmaxf(fminf(gy1[g], ay1) - fmaxf(gy0[g], ay0), 0.0f);
    float inter = iw * ih;
    float iou = inter * frcp(gar[g] + aar - inter);
    if (iou > best) { best = iou; bi = g; }   // first max wins
  }
  match[b * AA + a] = (best > 0.5f) ? bi : -1;
}

// ============ kernel B: streaming loss ∥ stage-B matcher ============
// grid (NLB+GG, B), 256 threads.
//  x in [0,NLB): champion streaming loss (match[] lookup; no bestp dependency)
//  x in [NLB,+GG): per-(b,g) best-anchor argmax -> bestp (consumed by k_C)
__global__ __launch_bounds__(256) void k_B(
    const float* __restrict__ pred, const float* __restrict__ anchors,
    const float* __restrict__ gt_boxes, const int* __restrict__ gt_labels,
    const int* __restrict__ gt_counts, const int* __restrict__ match,
    float* __restrict__ all_neg, float* __restrict__ partials,
    int* __restrict__ poscnts, int* __restrict__ bestp)
{
  const int b = blockIdx.y;
  const int tid = threadIdx.x;
  __shared__ float4 sgb[GG];
  __shared__ int slab[GG];
  __shared__ float wsum[4];
  __shared__ int wcnt[4];

  if (blockIdx.x < NLB) {
    // -------- loss block (byte-identical math to the 84.5µs champion) --------
    if (tid < GG) {
      sgb[tid] = reinterpret_cast<const float4*>(gt_boxes)[b * GG + tid];
      slab[tid] = gt_labels[b * GG + tid];
    }
    __syncthreads();

    const int abase = blockIdx.x * RPB * TILE;
    const int r = tid >> 2;
    const int sub = tid & 3;
    float acc = 0.0f;
    int poscnt = 0;

    for (int i = 0; i < RPB; ++i) {
      const int a0 = abase + i * TILE;
      if (a0 >= AA) break;
      const int a = a0 + r;
      if (a < AA) {
        const float* base = pred + ((size_t)b * AA + a) * DD;
        float4 s0 = *(const float4*)(base + (sub)      * 4);
        float4 s1 = *(const float4*)(base + (sub + 4)  * 4);
        float4 s2 = *(const float4*)(base + (sub + 8)  * 4);
        float4 s3 = *(const float4*)(base + (sub + 12) * 4);
        float4 s4 = *(const float4*)(base + (sub + 16) * 4);
        float4 s5f = make_float4(0.f, 0.f, 0.f, 0.f);
        float  s5x = 0.0f;
        if (sub == 0) s5f = *(const float4*)(base + 80);
        if (sub == 1) s5x = base[84];

        const int m = match[b * AA + a];
        const int tgt = (m >= 0) ? slab[m] + 1 : 0;

        const int cb = 4 * sub - 4;
        float mx = -INFINITY, xt = -INFINITY;
        #define SCAN(v, ccb)                                                 \
          { mx = fmaxf(fmaxf(fmaxf(mx, (v).x), (v).y), fmaxf((v).z, (v).w)); \
            if ((ccb) + 0 == tgt) xt = (v).x;                                \
            if ((ccb) + 1 == tgt) xt = (v).y;                                \
            if ((ccb) + 2 == tgt) xt = (v).z;                                \
            if ((ccb) + 3 == tgt) xt = (v).w; }
        if (sub > 0) SCAN(s0, cb);
        SCAN(s1, cb + 16); SCAN(s2, cb + 32); SCAN(s3, cb + 48); SCAN(s4, cb + 64);
        if (sub == 0) SCAN(s5f, 76);
        if (sub == 1) { mx = fmaxf(mx, s5x); if (tgt == 80) xt = s5x; }
        #undef SCAN
        #pragma unroll
        for (int msk = 1; msk <= 2; msk <<= 1)
          mx = fmaxf(mx, __shfl_xor(mx, msk));

        float s = 0.0f;
        #define ESUM(v) s += __expf((v).x - mx) + __expf((v).y - mx) +        \
                             __expf((v).z - mx) + __expf((v).w - mx);
        if (sub > 0) ESUM(s0);
        ESUM(s1); ESUM(s2); ESUM(s3); ESUM(s4);
        if (sub == 0) ESUM(s5f);
        if (sub == 1) s += __expf(s5x - mx);
        #undef ESUM
        #pragma unroll
        for (int msk = 1; msk <= 2; msk <<= 1) {
          s  += __shfl_xor(s, msk);
          xt  = fmaxf(xt, __shfl_xor(xt, msk));
        }
        const float lse = mx + __logf(s);
        const float ce = lse - xt;          // tgt==0 for negatives

        if (sub == 0) {
          if (m >= 0) {
            poscnt += 1;
            float4 an = reinterpret_cast<const float4*>(anchors)[a];
            float4 gb = sgb[m];
            float tx = (gb.x - an.x) / an.z;
            float ty = (gb.y - an.y) / an.w;
            float tw = __logf(gb.z) - __logf(an.z);
            float th = __logf(gb.w) - __logf(an.w);
            acc += smoothl1(s0.x - tx) + smoothl1(s0.y - ty)
                 + smoothl1(s0.z - tw) + smoothl1(s0.w - th) + ce;
            all_neg[b * AA + a] = 0.0f;
          } else {
            all_neg[b * AA + a] = fmaxf(ce, 0.0f);
          }
        }
      }
    }

    #pragma unroll
    for (int msk = 1; msk < 64; msk <<= 1) {
      acc    += __shfl_xor(acc, msk);
      poscnt += __shfl_xor(poscnt, msk);
    }
    if ((tid & 63) == 0) { wsum[tid >> 6] = acc; wcnt[tid >> 6] = poscnt; }
    __syncthreads();
    if (tid == 0) {
      partials[b * NLB + blockIdx.x] = (wsum[0] + wsum[1]) + (wsum[2] + wsum[3]);
      poscnts[b * NLB + blockIdx.x] = wcnt[0] + wcnt[1] + wcnt[2] + wcnt[3];
    }
  } else {
    // -------- stage-B block: per-(b,g) best anchor --------
    const int g = blockIdx.x - NLB;
    if (g >= gt_counts[b]) return;

    float4 gb = reinterpret_cast<const float4*>(gt_boxes)[b * GG + g];
    const float gx0s = gb.x - gb.z * 0.5f, gy0s = gb.y - gb.w * 0.5f;
    const float gx1s = gb.x + gb.z * 0.5f, gy1s = gb.y + gb.w * 0.5f;
    const float gars = (gx1s - gx0s) * (gy1s - gy0s);

    float bv = -2.0f; int bi = AA;
    for (int a = tid; a < AA; a += 256) {
      float4 an = reinterpret_cast<const float4*>(anchors)[a];
      float ax0 = an.x - an.z * 0.5f, ay0 = an.y - an.w * 0.5f;
      float ax1 = an.x + an.z * 0.5f, ay1 = an.y + an.w * 0.5f;
      float aar = (ax1 - ax0) * (ay1 - ay0);
      float iw = fmaxf(fminf(gx1s, ax1) - fmaxf(gx0s, ax0), 0.0f);
      float ih = fmaxf(fminf(gy1s, ay1) - fmaxf(gy0s, ay0), 0.0f);
      float inter = iw * ih;
      float iou = inter * frcp(gars + aar - inter);
      if (iou > bv || (iou == bv && a < bi)) { bv = iou; bi = a; }
    }
    #pragma unroll
    for (int m = 1; m < 64; m <<= 1) {
      float ov = __shfl_xor(bv, m);
      int   oi = __shfl_xor(bi, m);
      if (ov > bv || (ov == bv && oi < bi)) { bv = ov; bi = oi; }
    }
    if ((tid & 63) == 0) { wsum[tid >> 6] = bv; wcnt[tid >> 6] = bi; }
    __syncthreads();
    if (tid == 0) {
      float fv = wsum[0]; int fi = wcnt[0];
      #pragma unroll
      for (int w = 1; w < 4; ++w)
        if (wsum[w] > fv || (wsum[w] == fv && wcnt[w] < fi)) { fv = wsum[w]; fi = wcnt[w]; }
      bestp[b * GG + g] = fi;
    }
  }
}

// ============ kernel C: forced-match corrections + top-K select + out ============
__global__ __launch_bounds__(1024) void k_C(
    const float* __restrict__ pred, const float* __restrict__ anchors,
    const float* __restrict__ gt_boxes, const int* __restrict__ gt_labels,
    const int* __restrict__ gt_counts, const int* __restrict__ match,
    const float* __restrict__ all_neg, const float* __restrict__ partials,
    const int* __restrict__ poscnts, const int* __restrict__ bestp,
    float* __restrict__ batch_total, unsigned* __restrict__ epoch,
    float* __restrict__ out)
{
  const int b = blockIdx.x;
  const int tid = threadIdx.x;
  __shared__ unsigned u[AA];           // 34928 B
  __shared__ int hist16[16][257];
  __shared__ int hist[256];
  __shared__ float4 sgb[GG];
  __shared__ int slab[GG];
  __shared__ float sdelta[GG];
  __shared__ int sdnp[GG];
  __shared__ unsigned sh_pref;
  __shared__ int sh_k;
  __shared__ int sh_np;
  __shared__ float sh_base;
  __shared__ int sflag;
  __shared__ float wf[16];
  __shared__ int wc[16];

  // stage all_neg -> u (fire-and-forget)
  {
    const float* srcg = all_neg + (size_t)b * AA;
    #pragma unroll
    for (int j = 0; j < 3; ++j) {
      int c = j * 1024 + tid;
      if (c < 2183)
        __builtin_amdgcn_global_load_lds(
            (glb_u32*)(srcg + c * 4), (lds_u32*)((float*)u + c * 4), 16, 0, 0);
    }
  }
  if (tid < GG) {
    sgb[tid] = reinterpret_cast<const float4*>(gt_boxes)[b * GG + tid];
    slab[tid] = gt_labels[b * GG + tid];
    sdelta[tid] = 0.0f; sdnp[tid] = 0;
  }

  // wave-parallel partials / poscnt sums (overlap staging)
  float ps = 0.0f; int pc = 0;
  if (tid < 64) {
    float pv = (tid < NLB) ? partials[b * NLB + tid] : 0.0f;
    int   cv = (tid < NLB) ? poscnts[b * NLB + tid] : 0;
    #pragma unroll
    for (int m = 1; m < 64; m <<= 1) { pv += __shfl_xor(pv, m); cv += __shfl_xor(cv, m); }
    ps = pv; pc = cv;
  }
  __syncthreads();   // staging drained (vmcnt) + LDS init visible

  // -------- forced-match corrections (<=32 rows, m_old via match[] lookup) ----
  const int cnt = gt_counts[b];
  if (tid < cnt) {
    const int g = tid;
    const int p = bestp[b * GG + g];
    bool last = true;                      // ascending-g last-write-wins
    for (int g2 = g + 1; g2 < cnt; ++g2)
      if (bestp[b * GG + g2] == p) last = false;
    if (last) {
      const int m_old = match[b * AA + p];
      const float* row = pred + ((size_t)b * AA + p) * DD;
      float mx = -INFINITY;
      for (int c = 0; c < CC; ++c) mx = fmaxf(mx, row[4 + c]);
      float s = 0.0f;
      for (int c = 0; c < CC; ++c) s += __expf(row[4 + c] - mx);
      const float lse = mx + __logf(s);
      float4 an = reinterpret_cast<const float4*>(anchors)[p];

      auto posterm = [&](int m) -> float {
        const int tgt = slab[m] + 1;
        float ce = lse - row[4 + tgt];
        float4 gb = sgb[m];
        float tx = (gb.x - an.x) / an.z;
        float ty = (gb.y - an.y) / an.w;
        float tw = __logf(gb.z) - __logf(an.z);
        float th = __logf(gb.w) - __logf(an.w);
        return smoothl1(row[0] - tx) + smoothl1(row[1] - ty)
             + smoothl1(row[2] - tw) + smoothl1(row[3] - th) + ce;
      };
      sdelta[g] = posterm(g) - ((m_old >= 0) ? posterm(m_old) : 0.0f);
      sdnp[g] = (m_old < 0) ? 1 : 0;
      u[p] = 0u;                           // forced row is positive -> not a negative
    }
  }
  __syncthreads();

  if (tid == 0) {
    float dl = 0.0f; int dn = 0;
    for (int g = 0; g < cnt; ++g) { dl += sdelta[g]; dn += sdnp[g]; }
    const int npf = pc + dn;
    sh_np = npf;
    sh_base = ps + dl;
    sh_k = min(3 * npf, AA - 1);
  }
  __syncthreads();

  const int np = sh_np;
  const int wvid = tid >> 6;

  // -------- radix select (exact K-th largest) --------
  unsigned prefix = 0;
  int kk = sh_k;
  for (int shift = 24; shift >= 0; shift -= 8) {
    int* hflat = &hist16[0][0];
    for (int i = tid; i < 16 * 257; i += 1024) hflat[i] = 0;
    __syncthreads();
    const unsigned hmask = (shift == 24) ? 0u : (0xFFFFFFFFu << (shift + 8));
    for (int i = tid; i < AA; i += 1024) {
      unsigned x = u[i];
      if ((x & hmask) == prefix)
        atomicAdd(&hist16[wvid][(x >> shift) & 255], 1);
    }
    __syncthreads();
    if (tid < 256) {
      int s = 0;
      #pragma unroll
      for (int h = 0; h < 16; ++h) s += hist16[h][tid];
      hist[tid] = s;
    }
    __syncthreads();
    if (tid < 64) {
      int h0 = hist[4 * tid], h1 = hist[4 * tid + 1];
      int h2 = hist[4 * tid + 2], h3 = hist[4 * tid + 3];
      int lsum = h0 + h1 + h2 + h3;
      int suf = lsum;
      #pragma unroll
      for (int off = 1; off < 64; off <<= 1) {
        int o = __shfl_down(suf, off);
        suf += (tid + off < 64) ? o : 0;
      }
      int after = suf - lsum;
      int s3 = h3 + after, s2 = h2 + s3, s1 = h1 + s2, s0 = h0 + s1;
      if (s0 >= kk && s1 < kk)    { sh_pref = prefix | ((unsigned)(4*tid+0) << shift); sh_k = kk - s1; }
      if (s1 >= kk && s2 < kk)    { sh_pref = prefix | ((unsigned)(4*tid+1) << shift); sh_k = kk - s2; }
      if (s2 >= kk && s3 < kk)    { sh_pref = prefix | ((unsigned)(4*tid+2) << shift); sh_k = kk - s3; }
      if (s3 >= kk && after < kk) { sh_pref = prefix | ((unsigned)(4*tid+3) << shift); sh_k = kk - after; }
    }
    __syncthreads();
    prefix = sh_pref;
    kk = sh_k;
    __syncthreads();
  }
  const float tstar = __uint_as_float(prefix);
  const int K = min(3 * np, AA - 1);

  float ssum = 0.0f; int cgt = 0;
  for (int i = tid; i < AA; i += 1024) {
    float x = __uint_as_float(u[i]);
    if (x > tstar) { ssum += x; cgt += 1; }
  }
  #pragma unroll
  for (int m = 1; m < 64; m <<= 1) {
    ssum += __shfl_xor(ssum, m);
    cgt  += __shfl_xor(cgt, m);
  }
  if ((tid & 63) == 0) { wf[wvid] = ssum; wc[wvid] = cgt; }
  __syncthreads();
  if (tid == 0) {
    float S = 0.0f; int Cg = 0;
    #pragma unroll
    for (int w = 0; w < 16; ++w) { S += wf[w]; Cg += wc[w]; }
    float neg_sum = S + (float)(K - Cg) * tstar;
    batch_total[b] = (sh_base + neg_sum) / (float)np;
    __threadfence();                       // release (4B dirty: cheap)
    unsigned old = atomicAdd(epoch, 1u);
    sflag = (old == (unsigned)(BB - 1)) ? 1 : 0;
  }
  __syncthreads();

  if (sflag) {                             // 64th finisher: fixed-order final sum
    __threadfence();                       // acquire
    if (tid < 64) {
      float v = batch_total[tid];
      #pragma unroll
      for (int m = 1; m < 64; m <<= 1) v += __shfl_xor(v, m);
      if (tid == 0) out[0] = v;
    }
  }
}

extern "C" void kernel_launch(void* const* d_in, const int* in_sizes, int n_in,
                              void* d_out, int out_size, void* d_ws, size_t ws_size,
                              hipStream_t stream) {
  (void)in_sizes; (void)n_in; (void)out_size; (void)ws_size;
  const float* pred      = (const float*)d_in[0];
  const float* anchors   = (const float*)d_in[1];
  const float* gt_boxes  = (const float*)d_in[2];
  const int*   gt_labels = (const int*)d_in[3];
  const int*   gt_counts = (const int*)d_in[4];

  char* ws = (char*)d_ws;
  int*      match       = (int*)(ws + 0);
  float*    all_neg     = (float*)(ws + 2235392);
  float*    partials    = (float*)(ws + 4470784);
  int*      poscnts     = (int*)(ws + 4479744);
  float*    batch_total = (float*)(ws + 4488704);
  int*      bestp       = (int*)(ws + 4488960);
  unsigned* epoch       = (unsigned*)(ws + 4497152);
  float* out = (float*)d_out;

  hipLaunchKernelGGL(k_A, dim3(NLB, BB), dim3(256), 0, stream,
                     anchors, gt_boxes, gt_counts, match, epoch);
  hipLaunchKernelGGL(k_B, dim3(NLB + GG, BB), dim3(256), 0, stream,
                     pred, anchors, gt_boxes, gt_labels, gt_counts, match,
                     all_neg, partials, poscnts, bestp);
  hipLaunchKernelGGL(k_C, dim3(BB), dim3(1024), 0, stream,
                     pred, anchors, gt_boxes, gt_labels, gt_counts, match,
                     all_neg, partials, poscnts, bestp, batch_total, epoch, out);
}

// Round 15
// 80.190 us; speedup vs baseline: 1.1310x; 1.1310x over previous
//
#include <hip/hip_runtime.h>
#include <math.h>

#define BB 64
#define AA 8732
#define DD 85
#define GG 32
#define CC 81
#define TILE 64
#define RPB 4          /* 64-row groups per loss block -> 256 anchors/block */
#define NLB 35         /* loss blocks per batch (35*256 = 8960 >= 8732) */

// ---------------- workspace layout (bytes) ----------------
// all_neg:     0        .. 2235392   (B*A float)
// partials:    2235392  .. 2244352   (B*NLB float)
// batch_total: 2244352  .. 2244608   (B float)
// bestp:       2244608  .. 2252800   (B*G int32)
// n_pos:       2252800  .. 2253056   (B int32)   } zeroed by k_matchB g==0
// done_sel:    2253056  .. 2253060   (int32)     }

typedef __attribute__((address_space(3))) unsigned int lds_u32;
typedef const __attribute__((address_space(1))) unsigned int glb_u32;

__device__ __forceinline__ float smoothl1(float d) {
  float ad = fabsf(d);
  return ad < 1.0f ? 0.5f * d * d : ad - 0.5f;
}

__device__ __forceinline__ float frcp(float x) {
  return __builtin_amdgcn_rcpf(x);
}

// ============ kernel 1: stage-B matcher only (forced-match argmax) ============
// grid (GG, B), 256 threads; block (g,b) reduces over all 8732 anchors.
__global__ __launch_bounds__(256) void k_matchB(
    const float* __restrict__ anchors, const float* __restrict__ gt_boxes,
    const int* __restrict__ gt_counts, int* __restrict__ bestp,
    int* __restrict__ n_pos, int* __restrict__ done_sel)
{
  const int g = blockIdx.x;
  const int b = blockIdx.y;
  if (g == 0 && threadIdx.x == 0) {
    n_pos[b] = 0;
    if (b == 0) *done_sel = 0;
  }
  if (g >= gt_counts[b]) return;

  __shared__ float wv[4];
  __shared__ int wi[4];

  float4 gb = reinterpret_cast<const float4*>(gt_boxes)[b * GG + g];
  const float gx0s = gb.x - gb.z * 0.5f, gy0s = gb.y - gb.w * 0.5f;
  const float gx1s = gb.x + gb.z * 0.5f, gy1s = gb.y + gb.w * 0.5f;
  const float gars = (gx1s - gx0s) * (gy1s - gy0s);

  float bv = -2.0f; int bi = AA;
  for (int a = threadIdx.x; a < AA; a += 256) {
    float4 an = reinterpret_cast<const float4*>(anchors)[a];
    float ax0 = an.x - an.z * 0.5f, ay0 = an.y - an.w * 0.5f;
    float ax1 = an.x + an.z * 0.5f, ay1 = an.y + an.w * 0.5f;
    float aar = (ax1 - ax0) * (ay1 - ay0);
    float iw = fmaxf(fminf(gx1s, ax1) - fmaxf(gx0s, ax0), 0.0f);
    float ih = fmaxf(fminf(gy1s, ay1) - fmaxf(gy0s, ay0), 0.0f);
    float inter = iw * ih;
    float iou = inter * frcp(gars + aar - inter);
    if (iou > bv || (iou == bv && a < bi)) { bv = iou; bi = a; }
  }
  #pragma unroll
  for (int m = 1; m < 64; m <<= 1) {
    float ov = __shfl_xor(bv, m);
    int   oi = __shfl_xor(bi, m);
    if (ov > bv || (ov == bv && oi < bi)) { bv = ov; bi = oi; }
  }
  if ((threadIdx.x & 63) == 0) { wv[threadIdx.x >> 6] = bv; wi[threadIdx.x >> 6] = bi; }
  __syncthreads();
  if (threadIdx.x == 0) {
    float fv = wv[0]; int fi = wi[0];
    #pragma unroll
    for (int w = 1; w < 4; ++w)
      if (wv[w] > fv || (wv[w] == fv && wi[w] < fi)) { fv = wv[w]; fi = wi[w]; }
    bestp[b * GG + g] = fi;
  }
}

// ============ kernel 2: streaming loss with stage-A prologue ============
// grid (NLB, B), 256 threads, 4 threads/row.
// Prologue: one thread = one of the block's 256 anchors -> smatch[] in LDS
// (outside the row loop's critical path); bestp overrides via ovrg/atomicMax.
// Row loop: byte-identical math to the 84.5µs champion, but m comes from LDS
// (removes the per-row mid-compute global match[] load).
__global__ __launch_bounds__(256) void k_loss(
    const float* __restrict__ pred, const float* __restrict__ anchors,
    const float* __restrict__ gt_boxes, const int* __restrict__ gt_labels,
    const int* __restrict__ gt_counts, const int* __restrict__ bestp,
    float* __restrict__ all_neg, float* __restrict__ partials,
    int* __restrict__ n_pos)
{
  const int b = blockIdx.y;
  const int tid = threadIdx.x;
  const int abase = blockIdx.x * RPB * TILE;   // 256 anchors per block
  const int cnt = gt_counts[b];

  __shared__ float sgx0[GG], sgy0[GG], sgx1[GG], sgy1[GG], sgar[GG];
  __shared__ float4 sgb[GG];
  __shared__ int slab[GG];
  __shared__ int smatch[RPB * TILE];   // stage-A result per block anchor
  __shared__ int ovrg[RPB * TILE];     // forced-match override (max g)
  __shared__ float wsum[4];
  __shared__ int wcnt[4];

  if (tid < GG) {
    float4 gb = reinterpret_cast<const float4*>(gt_boxes)[b * GG + tid];
    sgb[tid] = gb;
    float x0 = gb.x - gb.z * 0.5f, y0 = gb.y - gb.w * 0.5f;
    float x1 = gb.x + gb.z * 0.5f, y1 = gb.y + gb.w * 0.5f;
    sgx0[tid] = x0; sgy0[tid] = y0; sgx1[tid] = x1; sgy1[tid] = y1;
    sgar[tid] = (x1 - x0) * (y1 - y0);
    slab[tid] = gt_labels[b * GG + tid];
  }
  ovrg[tid] = -1;
  __syncthreads();

  // ---- stage-A: one thread = one anchor (serial over g => first-max-wins) ----
  {
    const int a = abase + tid;
    int mres = -1;
    if (a < AA) {
      float4 an = reinterpret_cast<const float4*>(anchors)[a];
      float ax0 = an.x - an.z * 0.5f, ay0 = an.y - an.w * 0.5f;
      float ax1 = an.x + an.z * 0.5f, ay1 = an.y + an.w * 0.5f;
      float aar = (ax1 - ax0) * (ay1 - ay0);
      float best = -1.0f; int bi = 0;
      for (int g = 0; g < cnt; ++g) {
        float iw = fmaxf(fminf(sgx1[g], ax1) - fmaxf(sgx0[g], ax0), 0.0f);
        float ih = fmaxf(fminf(sgy1[g], ay1) - fmaxf(sgy0[g], ay0), 0.0f);
        float inter = iw * ih;
        float iou = inter * frcp(sgar[g] + aar - inter);
        if (iou > best) { best = iou; bi = g; }   // first max wins
      }
      mres = (best > 0.5f) ? bi : -1;
    }
    smatch[tid] = mres;
  }
  // forced-match scatter (max g == ascending last-write-wins)
  if (tid < GG && tid < cnt) {
    int p = bestp[b * GG + tid];
    int rel = p - abase;
    if (rel >= 0 && rel < RPB * TILE) atomicMax(&ovrg[rel], tid);
  }
  __syncthreads();

  const int r = tid >> 2;
  const int sub = tid & 3;
  float acc = 0.0f;
  int poscnt = 0;

  for (int i = 0; i < RPB; ++i) {
    const int a0 = abase + i * TILE;
    if (a0 >= AA) break;
    const int a = a0 + r;
    if (a < AA) {   // whole quad shares r -> uniform within the 4-lane group
      const float* base = pred + ((size_t)b * AA + a) * DD;
      float4 s0 = *(const float4*)(base + (sub)      * 4);
      float4 s1 = *(const float4*)(base + (sub + 4)  * 4);
      float4 s2 = *(const float4*)(base + (sub + 8)  * 4);
      float4 s3 = *(const float4*)(base + (sub + 12) * 4);
      float4 s4 = *(const float4*)(base + (sub + 16) * 4);
      float4 s5f = make_float4(0.f, 0.f, 0.f, 0.f);
      float  s5x = 0.0f;
      if (sub == 0) s5f = *(const float4*)(base + 80);  // chunk 20: cc 76..79
      if (sub == 1) s5x = base[84];                     // cc 80

      int m;
      { int o = ovrg[a - abase]; m = (o >= 0) ? o : smatch[a - abase]; }
      const int tgt = (m >= 0) ? slab[m] + 1 : 0;

      const int cb = 4 * sub - 4;
      float mx = -INFINITY, xt = -INFINITY;
      #define SCAN(v, ccb)                                                   \
        { mx = fmaxf(fmaxf(fmaxf(mx, (v).x), (v).y), fmaxf((v).z, (v).w));   \
          if ((ccb) + 0 == tgt) xt = (v).x;                                  \
          if ((ccb) + 1 == tgt) xt = (v).y;                                  \
          if ((ccb) + 2 == tgt) xt = (v).z;                                  \
          if ((ccb) + 3 == tgt) xt = (v).w; }
      if (sub > 0) SCAN(s0, cb);            // sub0 chunk0 is loc, not conf
      SCAN(s1, cb + 16); SCAN(s2, cb + 32); SCAN(s3, cb + 48); SCAN(s4, cb + 64);
      if (sub == 0) SCAN(s5f, 76);
      if (sub == 1) { mx = fmaxf(mx, s5x); if (tgt == 80) xt = s5x; }
      #undef SCAN
      #pragma unroll
      for (int msk = 1; msk <= 2; msk <<= 1)
        mx = fmaxf(mx, __shfl_xor(mx, msk));

      float s = 0.0f;
      #define ESUM(v) s += __expf((v).x - mx) + __expf((v).y - mx) +          \
                           __expf((v).z - mx) + __expf((v).w - mx);
      if (sub > 0) ESUM(s0);
      ESUM(s1); ESUM(s2); ESUM(s3); ESUM(s4);
      if (sub == 0) ESUM(s5f);
      if (sub == 1) s += __expf(s5x - mx);
      #undef ESUM
      #pragma unroll
      for (int msk = 1; msk <= 2; msk <<= 1) {
        s  += __shfl_xor(s, msk);
        xt  = fmaxf(xt, __shfl_xor(xt, msk));
      }
      const float lse = mx + __logf(s);
      const float ce = lse - xt;            // tgt==0 for negatives

      if (sub == 0) {
        if (m >= 0) {
          poscnt += 1;
          float4 an = reinterpret_cast<const float4*>(anchors)[a];
          float4 gb = sgb[m];
          float tx = (gb.x - an.x) / an.z;
          float ty = (gb.y - an.y) / an.w;
          float tw = __logf(gb.z) - __logf(an.z);
          float th = __logf(gb.w) - __logf(an.w);
          acc += smoothl1(s0.x - tx) + smoothl1(s0.y - ty)
               + smoothl1(s0.z - tw) + smoothl1(s0.w - th) + ce;
          all_neg[b * AA + a] = 0.0f;
        } else {
          all_neg[b * AA + a] = fmaxf(ce, 0.0f);
        }
      }
    }
  }

  #pragma unroll
  for (int msk = 1; msk < 64; msk <<= 1) {
    acc    += __shfl_xor(acc, msk);
    poscnt += __shfl_xor(poscnt, msk);
  }
  if ((tid & 63) == 0) {
    wsum[tid >> 6] = acc;
    wcnt[tid >> 6] = poscnt;
  }
  __syncthreads();
  if (tid == 0) {
    partials[b * NLB + blockIdx.x] = (wsum[0] + wsum[1]) + (wsum[2] + wsum[3]);
    int c = wcnt[0] + wcnt[1] + wcnt[2] + wcnt[3];
    if (c) atomicAdd(&n_pos[b], c);        // integer add: order-independent
  }
}

// ============ kernel 3: top-K select (champion, byte-identical) ============
__global__ __launch_bounds__(1024) void k_select(
    const float* __restrict__ all_neg, const float* __restrict__ partials,
    const int* __restrict__ n_pos, float* __restrict__ batch_total,
    int* __restrict__ done_sel, float* __restrict__ out)
{
  const int b = blockIdx.x;
  const int tid = threadIdx.x;
  __shared__ unsigned u[AA];           // 34928 B
  __shared__ int hist16[16][257];      // per-wave histograms
  __shared__ int hist[256];
  __shared__ unsigned sh_pref;
  __shared__ int sh_k;
  __shared__ int sflag;
  __shared__ float wf[16];
  __shared__ int wc[16];

  {
    const float* srcg = all_neg + (size_t)b * AA;   // 16B-aligned
    #pragma unroll
    for (int j = 0; j < 3; ++j) {
      int c = j * 1024 + tid;
      if (c < 2183)
        __builtin_amdgcn_global_load_lds(
            (glb_u32*)(srcg + c * 4), (lds_u32*)((float*)u + c * 4), 16, 0, 0);
    }
  }

  // wave-parallel partials sum (overlaps staging); NLB=35 spans 64 lanes
  float ps = 0.0f;
  if (tid < 64) {
    float pv = (tid < NLB) ? partials[b * NLB + tid] : 0.0f;
    #pragma unroll
    for (int m = 1; m < 64; m <<= 1) pv += __shfl_xor(pv, m);
    ps = pv;
  }
  __syncthreads();

  const int np = n_pos[b];
  const int K = min(3 * np, AA - 1);
  const int wvid = tid >> 6;

  unsigned prefix = 0;
  int kk = K;
  for (int shift = 24; shift >= 0; shift -= 8) {
    int* hflat = &hist16[0][0];
    for (int i = tid; i < 16 * 257; i += 1024) hflat[i] = 0;
    __syncthreads();
    const unsigned hmask = (shift == 24) ? 0u : (0xFFFFFFFFu << (shift + 8));
    for (int i = tid; i < AA; i += 1024) {
      unsigned x = u[i];
      if ((x & hmask) == prefix)
        atomicAdd(&hist16[wvid][(x >> shift) & 255], 1);
    }
    __syncthreads();
    if (tid < 256) {
      int s = 0;
      #pragma unroll
      for (int h = 0; h < 16; ++h) s += hist16[h][tid];
      hist[tid] = s;
    }
    __syncthreads();
    // barrier-free suffix scan + bin pick: wave 0 only
    if (tid < 64) {
      int h0 = hist[4 * tid], h1 = hist[4 * tid + 1];
      int h2 = hist[4 * tid + 2], h3 = hist[4 * tid + 3];
      int lsum = h0 + h1 + h2 + h3;
      int suf = lsum;
      #pragma unroll
      for (int off = 1; off < 64; off <<= 1) {
        int o = __shfl_down(suf, off);
        suf += (tid + off < 64) ? o : 0;
      }
      int after = suf - lsum;
      int s3 = h3 + after, s2 = h2 + s3, s1 = h1 + s2, s0 = h0 + s1;
      if (s0 >= kk && s1 < kk)    { sh_pref = prefix | ((unsigned)(4*tid+0) << shift); sh_k = kk - s1; }
      if (s1 >= kk && s2 < kk)    { sh_pref = prefix | ((unsigned)(4*tid+1) << shift); sh_k = kk - s2; }
      if (s2 >= kk && s3 < kk)    { sh_pref = prefix | ((unsigned)(4*tid+2) << shift); sh_k = kk - s3; }
      if (s3 >= kk && after < kk) { sh_pref = prefix | ((unsigned)(4*tid+3) << shift); sh_k = kk - after; }
    }
    __syncthreads();
    prefix = sh_pref;
    kk = sh_k;
    __syncthreads();
  }
  const float tstar = __uint_as_float(prefix);   // exact K-th largest

  float ssum = 0.0f; int cgt = 0;
  for (int i = tid; i < AA; i += 1024) {
    float x = __uint_as_float(u[i]);
    if (x > tstar) { ssum += x; cgt += 1; }
  }
  #pragma unroll
  for (int m = 1; m < 64; m <<= 1) {
    ssum += __shfl_xor(ssum, m);
    cgt  += __shfl_xor(cgt, m);
  }
  if ((tid & 63) == 0) { wf[wvid] = ssum; wc[wvid] = cgt; }
  __syncthreads();
  if (tid == 0) {
    float S = 0.0f; int Cg = 0;
    #pragma unroll
    for (int w = 0; w < 16; ++w) { S += wf[w]; Cg += wc[w]; }
    float neg_sum = S + (float)(K - Cg) * tstar;
    batch_total[b] = (ps + neg_sum) / (float)np;
    __threadfence();                       // release (4B dirty: cheap)
    int old = atomicAdd(done_sel, 1);
    sflag = (old == BB - 1) ? 1 : 0;
  }
  __syncthreads();

  if (sflag) {                             // last finishing block: final sum
    __threadfence();                       // acquire
    if (tid < 64) {
      float v = batch_total[tid];
      #pragma unroll
      for (int m = 1; m < 64; m <<= 1) v += __shfl_xor(v, m);
      if (tid == 0) out[0] = v;
    }
  }
}

extern "C" void kernel_launch(void* const* d_in, const int* in_sizes, int n_in,
                              void* d_out, int out_size, void* d_ws, size_t ws_size,
                              hipStream_t stream) {
  (void)in_sizes; (void)n_in; (void)out_size; (void)ws_size;
  const float* pred      = (const float*)d_in[0];
  const float* anchors   = (const float*)d_in[1];
  const float* gt_boxes  = (const float*)d_in[2];
  const int*   gt_labels = (const int*)d_in[3];
  const int*   gt_counts = (const int*)d_in[4];

  char* ws = (char*)d_ws;
  float* all_neg     = (float*)(ws + 0);
  float* partials    = (float*)(ws + 2235392);
  float* batch_total = (float*)(ws + 2244352);
  int*   bestp       = (int*)(ws + 2244608);
  int*   n_pos       = (int*)(ws + 2252800);
  int*   done_sel    = (int*)(ws + 2253056);
  float* out = (float*)d_out;

  hipLaunchKernelGGL(k_matchB, dim3(GG, BB), dim3(256), 0, stream,
                     anchors, gt_boxes, gt_counts, bestp, n_pos, done_sel);
  hipLaunchKernelGGL(k_loss, dim3(NLB, BB), dim3(256), 0, stream,
                     pred, anchors, gt_boxes, gt_labels, gt_counts, bestp,
                     all_neg, partials, n_pos);
  hipLaunchKernelGGL(k_select, dim3(BB), dim3(1024), 0, stream,
                     all_neg, partials, n_pos, batch_total, done_sel, out);
}